// Round 2
// baseline (619.307 us; speedup 1.0000x reference)
//
#include <hip/hip_runtime.h>

// PiecewiseContEmbeddings: B=4096, N=64, K=128, E=512, fp32.
//
// Identity: sorted boundaries => reference mask is [1...1, frac, 0...0], so
//   out[b,n,:] = relu( lerp(C[n,bidx,:], C[n,bidx+1,:], frac) )
// with C[n,j,:] = bias[n,:] + prefix_sum_{k<j} weight[n,k,:].
//
// R1 -> R2 changes:
//  - cumsum: 256 blocks x 128 thr (all CUs busy), nontemporal weight loads.
//  - idx: emits precomputed C row offset (element index), not bin index.
//  - gather: phase-aligned n-loop (all resident blocks share the same few C
//    rows -> L2-resident), float4 everywhere, nontemporal output stores so
//    the 536 MB write stream doesn't evict C from L2.

#define BB 4096
#define NN 64
#define KK 128
#define EE 512
#define EPSF 1e-8f

typedef float f32x4 __attribute__((ext_vector_type(4)));

// ---- Kernel 1: C[n,j,e] = bias[n,e] + sum_{k<j} weight[n,k,e], j in [0,K]
// grid = N * (E/128) = 256 blocks, 128 threads; one thread per (n,e) column.
__global__ void cumsum_kernel(const float* __restrict__ weight,
                              const float* __restrict__ bias,
                              float* __restrict__ C) {
    int n = blockIdx.x >> 2;
    int e = ((blockIdx.x & 3) << 7) + threadIdx.x;   // 0..511
    const float* w = weight + ((size_t)n * KK) * EE + e;
    float*       c = C + ((size_t)n * (KK + 1)) * EE + e;
    float run = bias[n * EE + e];
    c[0] = run;
#pragma unroll 8
    for (int k = 0; k < KK; ++k) {
        run += __builtin_nontemporal_load(w + (size_t)k * EE);
        c[(size_t)(k + 1) * EE] = run;
    }
}

// ---- Kernel 2: per (b,n) binary search -> C row offset + frac
__global__ void idx_kernel(const float* __restrict__ X,
                           const float* __restrict__ boundaries,
                           int* __restrict__ off_out,
                           float* __restrict__ frac_out) {
    int i = blockIdx.x * blockDim.x + threadIdx.x;   // b*N + n
    int n = i & (NN - 1);
    float x = X[i];
    const float* bnd = boundaries + n * (KK + 1);
    // lower_bound over inner = bnd[1 .. K-1]  (127 elements), result in [0,127]
    int lo = 0, hi = KK - 1;
    while (lo < hi) {
        int mid = (lo + hi) >> 1;
        if (bnd[1 + mid] < x) lo = mid + 1; else hi = mid;
    }
    float start = bnd[lo];
    float end   = bnd[lo + 1];
    off_out[i]  = (n * (KK + 1) + lo) * EE;          // element offset of C row
    frac_out[i] = (x - start) / (end - start + EPSF);
}

// ---- Kernel 3: out[b,n,:] = relu(lerp(C_row, C_row_next, frac))
// 2048 blocks x 256 thr. Each half-block (128 thr) owns one b and walks
// n = 0..63 in lockstep with every other block -> the live C working set at
// any instant is a handful of rows (L2-resident), not the whole 17 MB table.
__global__ void gather_kernel(const float* __restrict__ C,
                              const int* __restrict__ off_arr,
                              const float* __restrict__ frac,
                              float* __restrict__ out) {
    int half = threadIdx.x >> 7;                 // 0 or 1
    int ev   = threadIdx.x & 127;                // float4 index within row
    int b    = (blockIdx.x << 1) + half;
#pragma unroll 4
    for (int n = 0; n < NN; ++n) {
        int i = b * NN + n;
        int off = off_arr[i];
        float f = frac[i];
        const f32x4* p = (const f32x4*)(C + off) + ev;
        f32x4 lo = p[0];
        f32x4 hi = p[EE / 4];                    // next j row (+E floats)
        f32x4 r;
        r.x = fmaxf(fmaf(f, hi.x - lo.x, lo.x), 0.f);
        r.y = fmaxf(fmaf(f, hi.y - lo.y, lo.y), 0.f);
        r.z = fmaxf(fmaf(f, hi.z - lo.z, lo.z), 0.f);
        r.w = fmaxf(fmaf(f, hi.w - lo.w, lo.w), 0.f);
        f32x4* o = (f32x4*)(out + ((size_t)b * NN + n) * EE) + ev;
        __builtin_nontemporal_store(r, o);
    }
}

extern "C" void kernel_launch(void* const* d_in, const int* in_sizes, int n_in,
                              void* d_out, int out_size, void* d_ws, size_t ws_size,
                              hipStream_t stream) {
    const float* X          = (const float*)d_in[0];
    const float* boundaries = (const float*)d_in[1];
    const float* weight     = (const float*)d_in[2];
    const float* bias       = (const float*)d_in[3];
    float* out = (float*)d_out;

    // ws layout: C table | off | frac   (~18.2 MB total)
    float* C = (float*)d_ws;
    size_t Csz = (size_t)NN * (KK + 1) * EE;
    int*   off  = (int*)(C + Csz);
    float* frac = (float*)(off + (size_t)BB * NN);

    cumsum_kernel<<<NN * (EE / 128), 128, 0, stream>>>(weight, bias, C);
    idx_kernel<<<(BB * NN) / 256, 256, 0, stream>>>(X, boundaries, off, frac);
    gather_kernel<<<BB / 2, 256, 0, stream>>>(C, off, frac, out);
}